// Round 4
// baseline (82.029 us; speedup 1.0000x reference)
//
#include <hip/hip_runtime.h>

#define NB    512
#define FEAT  21609   // 21*21*7*7
#define CHW   6272    // 128*49
#define PLANE 5120    // 128 channels * 40-float padded block per j2-parity class
#define HV4   784     // float4s per half (64 channels) per array
#define HFLT  3136    // floats per half

__device__ __forceinline__ unsigned short f2bf(float x) {
    unsigned u = __float_as_uint(x);
    u += 0x7fffu + ((u >> 16) & 1u);   // round-to-nearest-even
    return (unsigned short)(u >> 16);
}
__device__ __forceinline__ float bf2f(unsigned short h) {
    return __uint_as_float((unsigned)h << 16);
}

__global__ __launch_bounds__(256) void corr_head_kernel(
    const float* __restrict__ patch1,
    const float* __restrict__ patch2,
    const float* __restrict__ w_bbox,
    const float* __restrict__ b_bbox,
    float* __restrict__ out)
{
    // s2p: value p2[c, 7*i2 + j2] at s2p[(j2&1)*PLANE + c*40 + i2*4 + (j2>>1)]
    // c-block 40 floats: i2=0..6 at [0,28), dummy i2=7 row [28,32) zeroed, [32,40) pad.
    __shared__ __align__(16) unsigned short s1b[CHW];       // p1 bf16 [c][ij], 12.5 KB
    __shared__ __align__(16) float          s2p[2 * PLANE]; // 40 KB
    __shared__ __align__(16) ushort4        s_wq[784];      // bf16 w4, (4t+u)*49+ij, 6.3 KB
    __shared__ float s_red[16];

    const int tid = threadIdx.x;
    const int b   = blockIdx.x;

    // ---- (a) zero dummy-readable slots (both halves) ----
    for (int n = tid; n < 1024; n += 256) {        // i2=7 dummy row of every (jp,c) block
        int jp = n >> 9, c = (n >> 2) & 127, u = n & 3;
        s2p[jp * PLANE + c * 40 + 28 + u] = 0.f;
    }
    for (int n = tid; n < 896; n += 256) {         // odd-class j2=7 dummy column
        int c = n / 7, i2 = n - 7 * c;
        s2p[PLANE + c * 40 + i2 * 4 + 3] = 0.f;
    }

    // ---- (b) issue ALL global loads up front: h0, h1 patches + w gathers ----
    const float4* g1 = (const float4*)(patch1 + (size_t)b * CHW);
    const float4* g2 = (const float4*)(patch2 + (size_t)b * CHW);
    float4 rp1[4], rp2[4], rq1[4], rq2[4];
    #pragma unroll
    for (int i = 0; i < 3; ++i) {
        rp1[i] = g1[tid + 256 * i];
        rp2[i] = g2[tid + 256 * i];
        rq1[i] = g1[HV4 + tid + 256 * i];
        rq2[i] = g2[HV4 + tid + 256 * i];
    }
    if (tid < 16) {                                 // 784 = 3*256 + 16 tail
        rp1[3] = g1[768 + tid];        rp2[3] = g2[768 + tid];
        rq1[3] = g1[HV4 + 768 + tid];  rq2[3] = g2[HV4 + 768 + tid];
    }

    float wv[4][4];
    #pragma unroll
    for (int i = 0; i < 4; ++i) {
        int n = tid + 256 * i;
        wv[i][0] = wv[i][1] = wv[i][2] = wv[i][3] = 0.f;
        if (n < 784) {
            int ij = n % 49, tu = n / 49;
            int t = tu >> 2, u = tu & 3;
            int ii = ij / 7, jj = ij - 7 * ii;
            int i2 = (ii & 1) + 2 * t, j2 = (jj & 1) + 2 * u;
            if (i2 < 7 && j2 < 7) {
                int p = 10 + ((i2 - ii) >> 1);
                int q = 10 + ((j2 - jj) >> 1);
                int f = ((p * 21 + q) * 7 + ii) * 7 + jj;
                wv[i][0] = w_bbox[f];
                wv[i][1] = w_bbox[FEAT + f];
                wv[i][2] = w_bbox[2 * FEAT + f];
                wv[i][3] = w_bbox[3 * FEAT + f];
            }
        }
    }

    // ---- (c) write h0 to LDS ----
    #pragma unroll
    for (int i = 0; i < 4; ++i) {
        if (i < 3 || tid < 16) {
            int t = tid + 256 * i;
            float4 v = rp1[i];
            ((ushort4*)s1b)[t] = make_ushort4(f2bf(v.x), f2bf(v.y), f2bf(v.z), f2bf(v.w));
            float4 w = rp2[i];
            int e = 4 * t;                     // flat < 3136, c < 64
            int c = e / 49, r = e - 49 * c;
            #pragma unroll
            for (int k = 0; k < 4; ++k) {
                int i2 = (r * 37) >> 8;        // r/7 for r<49
                int j2 = r - 7 * i2;
                s2p[(j2 & 1) * PLANE + c * 40 + i2 * 4 + (j2 >> 1)] = (&w.x)[k];
                if (++r == 49) { r = 0; ++c; }
            }
        }
    }
    __syncthreads();

    // ---- (d) compute h0 (cc 0..15) while h1 loads land ----
    const int ij = tid >> 2, cs = tid & 3;
    const int i = ij / 7, j = (tid < 196) ? (ij - 7 * i) : 0;
    const float* base2 = s2p + (j & 1) * PLANE + (i & 1) * 4;

    float dot[4][4];
    #pragma unroll
    for (int t = 0; t < 4; ++t)
        #pragma unroll
        for (int u = 0; u < 4; ++u) dot[t][u] = 0.f;

    if (tid < 196) {
        #pragma unroll 2
        for (int cc = 0; cc < 16; ++cc) {
            int c = cs + 4 * cc;
            float f1 = bf2f(s1b[c * 49 + ij]);
            const float* bc = base2 + c * 40;
            #pragma unroll
            for (int t = 0; t < 4; ++t) {
                float4 f2 = *(const float4*)(bc + 8 * t);
                dot[t][0] = fmaf(f1, f2.x, dot[t][0]);
                dot[t][1] = fmaf(f1, f2.y, dot[t][1]);
                dot[t][2] = fmaf(f1, f2.z, dot[t][2]);
                dot[t][3] = fmaf(f1, f2.w, dot[t][3]);
            }
        }
    }

    // ---- (e) write h1 to LDS (disjoint addresses from h0 reads — no barrier needed) ----
    #pragma unroll
    for (int i4 = 0; i4 < 4; ++i4) {
        if (i4 < 3 || tid < 16) {
            int t = tid + 256 * i4;
            float4 v = rq1[i4];
            ((ushort4*)s1b)[HV4 + t] = make_ushort4(f2bf(v.x), f2bf(v.y), f2bf(v.z), f2bf(v.w));
            float4 w = rq2[i4];
            int e = HFLT + 4 * t;              // c in [64,128)
            int c = e / 49, r = e - 49 * c;
            #pragma unroll
            for (int k = 0; k < 4; ++k) {
                int i2 = (r * 37) >> 8;
                int j2 = r - 7 * i2;
                s2p[(j2 & 1) * PLANE + c * 40 + i2 * 4 + (j2 >> 1)] = (&w.x)[k];
                if (++r == 49) { r = 0; ++c; }
            }
        }
    }

    // ---- (f) build weight table from pre-loaded values ----
    #pragma unroll
    for (int i4 = 0; i4 < 4; ++i4) {
        int n = tid + 256 * i4;
        if (n < 784)
            s_wq[n] = make_ushort4(f2bf(wv[i4][0]), f2bf(wv[i4][1]),
                                   f2bf(wv[i4][2]), f2bf(wv[i4][3]));
    }
    __syncthreads();

    // ---- (g) compute h1 (cc 16..31) ----
    if (tid < 196) {
        #pragma unroll 2
        for (int cc = 16; cc < 32; ++cc) {
            int c = cs + 4 * cc;
            float f1 = bf2f(s1b[c * 49 + ij]);
            const float* bc = base2 + c * 40;
            #pragma unroll
            for (int t = 0; t < 4; ++t) {
                float4 f2 = *(const float4*)(bc + 8 * t);
                dot[t][0] = fmaf(f1, f2.x, dot[t][0]);
                dot[t][1] = fmaf(f1, f2.y, dot[t][1]);
                dot[t][2] = fmaf(f1, f2.z, dot[t][2]);
                dot[t][3] = fmaf(f1, f2.w, dot[t][3]);
            }
        }
    }

    // ---- (h) per-thread weighting + reduction ----
    float a0 = 0.f, a1 = 0.f, a2 = 0.f, a3 = 0.f;
    if (tid < 196) {
        #pragma unroll
        for (int t = 0; t < 4; ++t)
            #pragma unroll
            for (int u = 0; u < 4; ++u) {
                ushort4 wq = s_wq[(4 * t + u) * 49 + ij];
                float d = dot[t][u];
                a0 = fmaf(d, bf2f(wq.x), a0);
                a1 = fmaf(d, bf2f(wq.y), a1);
                a2 = fmaf(d, bf2f(wq.z), a2);
                a3 = fmaf(d, bf2f(wq.w), a3);
            }
    }

    for (int off = 32; off > 0; off >>= 1) {
        a0 += __shfl_down(a0, off, 64);
        a1 += __shfl_down(a1, off, 64);
        a2 += __shfl_down(a2, off, 64);
        a3 += __shfl_down(a3, off, 64);
    }
    if ((tid & 63) == 0) {
        int w = tid >> 6;
        s_red[w * 4 + 0] = a0;
        s_red[w * 4 + 1] = a1;
        s_red[w * 4 + 2] = a2;
        s_red[w * 4 + 3] = a3;
    }
    __syncthreads();
    if (tid < 4) {
        float r = s_red[tid] + s_red[4 + tid] + s_red[8 + tid] + s_red[12 + tid];
        out[b * 4 + tid] = r + b_bbox[tid];
    }
}

extern "C" void kernel_launch(void* const* d_in, const int* in_sizes, int n_in,
                              void* d_out, int out_size, void* d_ws, size_t ws_size,
                              hipStream_t stream) {
    const float* patch1 = (const float*)d_in[0];
    const float* patch2 = (const float*)d_in[1];
    const float* w_bbox = (const float*)d_in[2];
    const float* b_bbox = (const float*)d_in[3];
    float* out = (float*)d_out;
    corr_head_kernel<<<dim3(NB), dim3(256), 0, stream>>>(patch1, patch2, w_bbox, b_bbox, out);
}

// Round 5
// 78.924 us; speedup vs baseline: 1.0393x; 1.0393x over previous
//
#include <hip/hip_runtime.h>

#define NB    512
#define FEAT  21609   // 21*21*7*7
#define CHW   6272    // 128*49
#define NV4   1568    // CHW/4
#define PLANE 5120    // 128 channels * 40-float padded block per j2-parity class

// 49 ij's grouped into 25 same-parity-class slots (pairs; slot 24 is a singleton).
// classes: (i&1,j&1)=ee 16, eo 12, oe 12, oo 9
__constant__ unsigned char c_pa[25] = {0,4,14,18,28,32,42,46,  1,5,17,29,33,45,
                                       7,11,21,25,35,39,       8,12,24,36,40};
__constant__ unsigned char c_pb[25] = {2,6,16,20,30,34,44,48,  3,15,19,31,43,47,
                                       9,13,23,27,37,41,       10,22,26,38,255};

__device__ __forceinline__ unsigned short f2bf(float x) {
    unsigned u = __float_as_uint(x);
    u += 0x7fffu + ((u >> 16) & 1u);   // round-to-nearest-even
    return (unsigned short)(u >> 16);
}
__device__ __forceinline__ float bf2f(unsigned short h) {
    return __uint_as_float((unsigned)h << 16);
}

__global__ __launch_bounds__(256) void corr_head_kernel(
    const float* __restrict__ patch1,
    const float* __restrict__ patch2,
    const float* __restrict__ w_bbox,
    const float* __restrict__ b_bbox,
    float* __restrict__ out)
{
    // s2p: value p2[c, 7*i2 + j2] at s2p[(j2&1)*PLANE + c*40 + i2*4 + (j2>>1)]
    // c-block 40 floats: i2=0..6 at [0,28), dummy i2=7 row [28,32) zeroed, [32,40) pad.
    __shared__ __align__(16) unsigned short s1b[CHW];        // p1 bf16 [c][ij], 12.5 KB
    __shared__ __align__(16) float          s2p[2 * PLANE];  // 40 KB
    __shared__ __align__(16) ushort4        s_wq[784];       // bf16 w4, (4t+u)*49+ij, 6.3 KB
    __shared__ float s_red[16];

    const int tid = threadIdx.x;
    const int b   = blockIdx.x;

    // ---- zero dummy-readable slots ----
    for (int n = tid; n < 1024; n += 256) {        // i2=7 dummy row of every (jp,c) block
        int jp = n >> 9, c = (n >> 2) & 127, u = n & 3;
        s2p[jp * PLANE + c * 40 + 28 + u] = 0.f;
    }
    for (int n = tid; n < 896; n += 256) {         // odd-class j2=7 dummy column
        int c = n / 7, i2 = n - 7 * c;
        s2p[PLANE + c * 40 + i2 * 4 + 3] = 0.f;
    }

    // ---- stage p1 -> bf16 LDS (coalesced f4 load, b64 store) ----
    const float4* g1 = (const float4*)(patch1 + (size_t)b * CHW);
    for (int t = tid; t < NV4; t += 256) {
        float4 v = g1[t];
        ((ushort4*)s1b)[t] = make_ushort4(f2bf(v.x), f2bf(v.y), f2bf(v.z), f2bf(v.w));
    }

    // ---- stage p2 -> parity-split layout (scatter b32, ~2-way banks) ----
    const float4* g2 = (const float4*)(patch2 + (size_t)b * CHW);
    for (int t = tid; t < NV4; t += 256) {
        float4 v = g2[t];
        int e = t * 4;
        int c = e / 49;
        int r = e - 49 * c;
        #pragma unroll
        for (int k = 0; k < 4; ++k) {
            int i2 = (r * 37) >> 8;     // r/7 for r<49
            int j2 = r - 7 * i2;
            s2p[(j2 & 1) * PLANE + c * 40 + i2 * 4 + (j2 >> 1)] = (&v.x)[k];
            if (++r == 49) { r = 0; ++c; }
        }
    }

    // ---- build bf16 weight table: entry (4t+u)*49+ij = w4 for (i2=(i&1)+2t, j2=(j&1)+2u) ----
    for (int n = tid; n < 784; n += 256) {
        int ij = n % 49, tu = n / 49;
        int t = tu >> 2, u = tu & 3;
        int i = ij / 7, j = ij - 7 * i;
        int i2 = (i & 1) + 2 * t, j2 = (j & 1) + 2 * u;
        ushort4 wq = make_ushort4(0, 0, 0, 0);
        if (i2 < 7 && j2 < 7) {
            int p = 10 + ((i2 - i) >> 1);
            int q = 10 + ((j2 - j) >> 1);
            int f = ((p * 21 + q) * 7 + i) * 7 + j;
            wq = make_ushort4(f2bf(w_bbox[f]), f2bf(w_bbox[FEAT + f]),
                              f2bf(w_bbox[2 * FEAT + f]), f2bf(w_bbox[3 * FEAT + f]));
        }
        s_wq[n] = wq;
    }
    __syncthreads();

    // ---- main: thread (slot = tid>>3 owns 2 same-class ij's, cs = tid&7 -> c = cs+8cc) ----
    float a0 = 0.f, a1 = 0.f, a2 = 0.f, a3 = 0.f;
    if (tid < 200) {
        const int slot = tid >> 3, cs = tid & 7;
        const int ija  = c_pa[slot];
        const int ijbr = c_pb[slot];
        const bool has_b = (ijbr < 49);
        const int ijb  = has_b ? ijbr : ija;     // safe reads; discarded at weighting
        const int i = ija / 7, j = ija - 7 * i;  // parity class shared by ija/ijb
        const float* base2 = s2p + (j & 1) * PLANE + (i & 1) * 4;

        float da[4][4], db[4][4];
        #pragma unroll
        for (int t = 0; t < 4; ++t)
            #pragma unroll
            for (int u = 0; u < 4; ++u) { da[t][u] = 0.f; db[t][u] = 0.f; }

        #pragma unroll 2
        for (int cc = 0; cc < 16; ++cc) {
            int c = cs + 8 * cc;
            float f1a = bf2f(s1b[c * 49 + ija]);
            float f1b = bf2f(s1b[c * 49 + ijb]);
            const float* bc = base2 + c * 40;
            #pragma unroll
            for (int t = 0; t < 4; ++t) {
                float4 f2 = *(const float4*)(bc + 8 * t);
                da[t][0] = fmaf(f1a, f2.x, da[t][0]);
                da[t][1] = fmaf(f1a, f2.y, da[t][1]);
                da[t][2] = fmaf(f1a, f2.z, da[t][2]);
                da[t][3] = fmaf(f1a, f2.w, da[t][3]);
                db[t][0] = fmaf(f1b, f2.x, db[t][0]);
                db[t][1] = fmaf(f1b, f2.y, db[t][1]);
                db[t][2] = fmaf(f1b, f2.z, db[t][2]);
                db[t][3] = fmaf(f1b, f2.w, db[t][3]);
            }
        }

        // ---- weighting (w amortized over 128 channels via 8 channel-lanes) ----
        #pragma unroll
        for (int t = 0; t < 4; ++t)
            #pragma unroll
            for (int u = 0; u < 4; ++u) {
                ushort4 wq = s_wq[(4 * t + u) * 49 + ija];
                float d = da[t][u];
                a0 = fmaf(d, bf2f(wq.x), a0);
                a1 = fmaf(d, bf2f(wq.y), a1);
                a2 = fmaf(d, bf2f(wq.z), a2);
                a3 = fmaf(d, bf2f(wq.w), a3);
            }
        if (has_b) {
            #pragma unroll
            for (int t = 0; t < 4; ++t)
                #pragma unroll
                for (int u = 0; u < 4; ++u) {
                    ushort4 wq = s_wq[(4 * t + u) * 49 + ijb];
                    float d = db[t][u];
                    a0 = fmaf(d, bf2f(wq.x), a0);
                    a1 = fmaf(d, bf2f(wq.y), a1);
                    a2 = fmaf(d, bf2f(wq.z), a2);
                    a3 = fmaf(d, bf2f(wq.w), a3);
                }
        }
    }

    // ---- reduce 256 threads -> 4 outputs ----
    for (int off = 32; off > 0; off >>= 1) {
        a0 += __shfl_down(a0, off, 64);
        a1 += __shfl_down(a1, off, 64);
        a2 += __shfl_down(a2, off, 64);
        a3 += __shfl_down(a3, off, 64);
    }
    if ((tid & 63) == 0) {
        int w = tid >> 6;
        s_red[w * 4 + 0] = a0;
        s_red[w * 4 + 1] = a1;
        s_red[w * 4 + 2] = a2;
        s_red[w * 4 + 3] = a3;
    }
    __syncthreads();
    if (tid < 4) {
        float r = s_red[tid] + s_red[4 + tid] + s_red[8 + tid] + s_red[12 + tid];
        out[b * 4 + tid] = r + b_bbox[tid];
    }
}

extern "C" void kernel_launch(void* const* d_in, const int* in_sizes, int n_in,
                              void* d_out, int out_size, void* d_ws, size_t ws_size,
                              hipStream_t stream) {
    const float* patch1 = (const float*)d_in[0];
    const float* patch2 = (const float*)d_in[1];
    const float* w_bbox = (const float*)d_in[2];
    const float* b_bbox = (const float*)d_in[3];
    float* out = (float*)d_out;
    corr_head_kernel<<<dim3(NB), dim3(256), 0, stream>>>(patch1, patch2, w_bbox, b_bbox, out);
}